// Round 7
// baseline (223.156 us; speedup 1.0000x reference)
//
#include <hip/hip_runtime.h>
#include <math.h>

typedef __bf16 bf16x8 __attribute__((ext_vector_type(8)));
typedef __bf16 bf16x2 __attribute__((ext_vector_type(2)));
typedef float f32x4 __attribute__((ext_vector_type(4)));
typedef float f32x16 __attribute__((ext_vector_type(16)));
typedef unsigned u32x2v __attribute__((ext_vector_type(2)));
typedef unsigned short u16;

#define NQ 8192
#define DMODEL 512
#define NHEAD 8
#define DH 64
#define NC 2048
#define NIDX 100000

__device__ __forceinline__ u16 f2bf(float f) {
    unsigned u = __float_as_uint(f);
    u += 0x7fffu + ((u >> 16) & 1u);
    return (u16)(u >> 16);
}
__device__ __forceinline__ float bf2f(u16 h) {
    return __uint_as_float(((unsigned)h) << 16);
}
__device__ __forceinline__ unsigned pk2(float a, float b) {
    bf16x2 t; t[0] = (__bf16)a; t[1] = (__bf16)b;   // v_cvt_pk_bf16_f32
    return __builtin_bit_cast(unsigned, t);
}
// permlane32_swap via builtin (correct regalloc even with aliased inputs):
// a' = (a.lo, b.lo-content-in-hi), b' = (a.hi-content-in-lo, b.hi)
__device__ __forceinline__ void plswap(unsigned& a, unsigned& b) {
    u32x2v r = __builtin_amdgcn_permlane32_swap(a, b, false, false);
    a = r[0]; b = r[1];
}
// swizzled u32 index into sO[32][256]: 16B-block XOR by row
__device__ __forceinline__ int soff(int q, int col) {
    return q * 256 + ((((col >> 2) ^ (q & 7)) << 2) | (col & 3));
}

// ---------------- fused preamble: converts + transposes + hist + bcomb ----------------
__global__ __launch_bounds__(256) void k_prep(
    const float* __restrict__ x, const float* __restrict__ kb, const float* __restrict__ vb,
    const float* __restrict__ Wp, const float* __restrict__ Wq, const float* __restrict__ Wk,
    const float* __restrict__ Wv, const float* __restrict__ bp, const float* __restrict__ bq_,
    const int* __restrict__ cidx,
    u16* __restrict__ x_bf, u16* __restrict__ kb_bf, u16* __restrict__ vb_bf,
    u16* __restrict__ Wp_bf, u16* __restrict__ Wq_t, u16* __restrict__ Wk_t,
    u16* __restrict__ Wv_t, int* __restrict__ counts, float* __restrict__ bcomb)
{
    __shared__ float tile[32][33];
    int bid = blockIdx.x, tid = threadIdx.x;
    if (bid < 6400) {
        const float* src; u16* dst; int i;
        if (bid < 4096)      { src = x;  dst = x_bf;  i = bid; }
        else if (bid < 5120) { src = kb; dst = kb_bf; i = bid - 4096; }
        else if (bid < 6144) { src = vb; dst = vb_bf; i = bid - 5120; }
        else                 { src = Wp; dst = Wp_bf; i = bid - 6144; }
        int e = (i * 256 + tid) * 4;
        float4 v = *(const float4*)(src + e);
        ushort4 o;
        o.x = f2bf(v.x); o.y = f2bf(v.y); o.z = f2bf(v.z); o.w = f2bf(v.w);
        *(ushort4*)(dst + e) = o;
    } else if (bid < 7168) {
        const float* W; u16* Wt; int tb;
        if (bid < 6656)      { W = Wq; Wt = Wq_t; tb = bid - 6400; }
        else if (bid < 6912) { W = Wk; Wt = Wk_t; tb = bid - 6656; }
        else                 { W = Wv; Wt = Wv_t; tb = bid - 6912; }
        int c0 = (tb & 15) * 32, r0 = (tb >> 4) * 32;
        int tx = tid & 31, ty = tid >> 5;
#pragma unroll
        for (int i = 0; i < 4; i++)
            tile[ty + i * 8][tx] = W[(size_t)(r0 + ty + i * 8) * DMODEL + c0 + tx];
        __syncthreads();
#pragma unroll
        for (int i = 0; i < 4; i++)
            Wt[(size_t)(c0 + ty + i * 8) * DMODEL + r0 + tx] = f2bf(tile[tx][ty + i * 8]);
    } else if (bid < 7296) {
        for (int i = (bid - 7168) * 256 + tid; i < NIDX; i += 128 * 256)
            atomicAdd(&counts[cidx[i]], 1);
    } else {
        int j = (bid - 7296) * 256 + tid;
        float s = bq_[j];
        for (int k = 0; k < DMODEL; k++) s += bp[k] * Wq[(size_t)k * DMODEL + j];
        bcomb[j] = s;
    }
}

// ---------------- bf16 GEMM: C = A[M][K] * Bt[N][K]^T + bias[N] ----------------
template <int OUT_T>
__global__ __launch_bounds__(256) void k_gemm_bt(
    const u16* __restrict__ A, const u16* __restrict__ Bt,
    const float* __restrict__ bias, u16* __restrict__ Cmat,
    int M, int N, int K)
{
    constexpr int LDP = 40;
    __shared__ __align__(16) u16 As[128 * LDP];
    __shared__ __align__(16) u16 Bs[128 * LDP];
    int tid = threadIdx.x;
    int lane = tid & 63, wid = tid >> 6;
    int wrow = (wid >> 1) * 64, wcol = (wid & 1) * 64;
    int m0 = blockIdx.y * 128, n0 = blockIdx.x * 128;
    int lr = lane & 15, lg = lane >> 4;
    f32x4 acc[4][4] = {};

    for (int k0 = 0; k0 < K; k0 += 32) {
#pragma unroll
        for (int c = 0; c < 2; c++) {
            int ch = tid + c * 256;
            int row = ch >> 2, colc = (ch & 3) * 8;
            uint4 av = *(const uint4*)(A + (size_t)(m0 + row) * K + k0 + colc);
            *(uint4*)(&As[row * LDP + colc]) = av;
            uint4 bv = *(const uint4*)(Bt + (size_t)(n0 + row) * K + k0 + colc);
            *(uint4*)(&Bs[row * LDP + colc]) = bv;
        }
        __syncthreads();
        bf16x8 af[4], bfr[4];
#pragma unroll
        for (int m = 0; m < 4; m++)
            af[m] = *(const bf16x8*)(&As[(wrow + m * 16 + lr) * LDP + lg * 8]);
#pragma unroll
        for (int n = 0; n < 4; n++)
            bfr[n] = *(const bf16x8*)(&Bs[(wcol + n * 16 + lr) * LDP + lg * 8]);
#pragma unroll
        for (int m = 0; m < 4; m++)
#pragma unroll
            for (int n = 0; n < 4; n++)
                acc[m][n] = __builtin_amdgcn_mfma_f32_16x16x32_bf16(af[m], bfr[n], acc[m][n], 0, 0, 0);
        __syncthreads();
    }
#pragma unroll
    for (int n = 0; n < 4; n++) {
        int col = n0 + wcol + n * 16 + lr;
        float bv = bias ? bias[col] : 0.0f;
#pragma unroll
        for (int m = 0; m < 4; m++) {
            int rbase = m0 + wrow + m * 16 + lg * 4;
            if (OUT_T) {
                ushort4 o4;
                o4.x = f2bf(acc[m][n][0] + bv);
                o4.y = f2bf(acc[m][n][1] + bv);
                o4.z = f2bf(acc[m][n][2] + bv);
                o4.w = f2bf(acc[m][n][3] + bv);
                *(ushort4*)(Cmat + (size_t)col * M + rbase) = o4;
            } else {
#pragma unroll
                for (int r = 0; r < 4; r++)
                    Cmat[(size_t)(rbase + r) * N + col] = f2bf(acc[m][n][r] + bv);
            }
        }
    }
}

// ---------------- fused attention + LayerNorm ----------------
// grid(NQ/32); block 512 = 8 waves = 8 heads. Wave: 32 q-rows, one head, all 2048
// centroids, TWO 32-c chunks per iteration (independent chains = in-wave ILP).
// Swapped QK^T (mfma(K,Q)) -> lane-local softmax; P half-exchange via
// __builtin_amdgcn_permlane32_swap; scalar reduces via __shfl_xor (proven).
__global__ __launch_bounds__(512, 2) void k_attn5(
    const u16* __restrict__ Q, const u16* __restrict__ Km, const u16* __restrict__ Vt,
    const int* __restrict__ counts, const float* __restrict__ ln_g,
    const float* __restrict__ ln_b, float* __restrict__ Out, float scale2)
{
    __shared__ float sbias[NC];          // 8 KB, log2(count)
    __shared__ unsigned sO[32 * 256];    // 32 KB, swizzled packed O

    int tid = threadIdx.x;
    int lane = tid & 63, wid = tid >> 6;
    int h = wid;
    int ql = lane & 31, hi = lane >> 5;
    int q0 = blockIdx.x * 32;
    int hbase = h * DH;

#pragma unroll
    for (int i = 0; i < 4; i++)
        sbias[tid + i * 512] = log2f((float)counts[tid + i * 512]);

    bf16x8 qf[4];
#pragma unroll
    for (int m = 0; m < 4; m++)
        qf[m] = *(const bf16x8*)(Q + (size_t)(q0 + ql) * DMODEL + hbase + m * 16 + hi * 8);

    const u16* kbase = Km + (size_t)ql * DMODEL + hbase + hi * 8;
    const u16* vbase = Vt + (size_t)(hbase + ql) * NC + hi * 8;

    // preload chunks 0 (A) and 1 (B): K and V fragments
    bf16x8 kfA[4], kfB[4], vfA[4], vfB[4];
#pragma unroll
    for (int m = 0; m < 4; m++) {
        kfA[m] = *(const bf16x8*)(kbase + (size_t)0 * DMODEL + m * 16);
        kfB[m] = *(const bf16x8*)(kbase + (size_t)32 * DMODEL + m * 16);
    }
#pragma unroll
    for (int T = 0; T < 2; T++)
#pragma unroll
        for (int ss = 0; ss < 2; ss++) {
            vfA[T * 2 + ss] = *(const bf16x8*)(vbase + (size_t)(T * 32) * NC + 0 + ss * 16);
            vfB[T * 2 + ss] = *(const bf16x8*)(vbase + (size_t)(T * 32) * NC + 32 + ss * 16);
        }

    f32x16 o0 = {}, o1 = {};
    float m_run = -1e30f, l_part = 0.f;

    __syncthreads();   // sbias ready

    for (int t = 0; t < NC / 64; t++) {
        int cA = t * 64, cB = cA + 32, cN = cA + 64;   // wrap-free; tail prefetch lands in padded ws

        f32x4 bqA[4], bqB[4];
#pragma unroll
        for (int j = 0; j < 4; j++) {
            bqA[j] = *(const f32x4*)(sbias + cA + 8 * j + 4 * hi);
            bqB[j] = *(const f32x4*)(sbias + cB + 8 * j + 4 * hi);
        }

        // QK^T both chunks (independent chains): acc[c][q]
        f32x16 accA = {}, accB = {};
        __builtin_amdgcn_s_setprio(1);
#pragma unroll
        for (int m = 0; m < 4; m++)
            accA = __builtin_amdgcn_mfma_f32_32x32x16_bf16(kfA[m], qf[m], accA, 0, 0, 0);
#pragma unroll
        for (int m = 0; m < 4; m++)
            accB = __builtin_amdgcn_mfma_f32_32x32x16_bf16(kfB[m], qf[m], accB, 0, 0, 0);
        __builtin_amdgcn_s_setprio(0);

        // prefetch next K pair into just-freed regs
#pragma unroll
        for (int m = 0; m < 4; m++) {
            kfA[m] = *(const bf16x8*)(kbase + (size_t)cN * DMODEL + m * 16);
            kfB[m] = *(const bf16x8*)(kbase + (size_t)(cN + 32) * DMODEL + m * 16);
        }

        float sA[16], sB[16];
#pragma unroll
        for (int r = 0; r < 16; r++) {
            sA[r] = accA[r] * scale2 + bqA[r >> 2][r & 3];
            sB[r] = accB[r] * scale2 + bqB[r >> 2][r & 3];
        }

        float mx = fmaxf(sA[0], sB[0]);
#pragma unroll
        for (int r = 1; r < 16; r++) mx = fmaxf(mx, fmaxf(sA[r], sB[r]));
        mx = fmaxf(mx, __shfl_xor(mx, 32));   // cross-half reduce (proven path)

        if (__any(mx > m_run + 11.f)) {            // defer-max (log2 domain)
            float mn = fmaxf(m_run, mx);
            float corr = exp2f(m_run - mn);
            m_run = mn; l_part *= corr;
#pragma unroll
            for (int r = 0; r < 16; r++) { o0[r] *= corr; o1[r] *= corr; }
        }

        float rs = 0.f;
#pragma unroll
        for (int r = 0; r < 16; r++) {
            sA[r] = exp2f(sA[r] - m_run);
            sB[r] = exp2f(sB[r] - m_run);
            rs += sA[r] + sB[r];
        }
        l_part += rs;

        // pack P pairs; half-exchange: plswap(u[j], u[j+2]) -> word_j, word_{j+2}
        unsigned uA[8], uB[8];
#pragma unroll
        for (int j = 0; j < 8; j++) {
            uA[j] = pk2(sA[2 * j], sA[2 * j + 1]);
            uB[j] = pk2(sB[2 * j], sB[2 * j + 1]);
        }
        plswap(uA[0], uA[2]); plswap(uA[1], uA[3]);
        plswap(uA[4], uA[6]); plswap(uA[5], uA[7]);
        plswap(uB[0], uB[2]); plswap(uB[1], uB[3]);
        plswap(uB[4], uB[6]); plswap(uB[5], uB[7]);
        bf16x8 pA0 = __builtin_bit_cast(bf16x8, *(uint4*)&uA[0]);
        bf16x8 pA1 = __builtin_bit_cast(bf16x8, *(uint4*)&uA[4]);
        bf16x8 pB0 = __builtin_bit_cast(bf16x8, *(uint4*)&uB[0]);
        bf16x8 pB1 = __builtin_bit_cast(bf16x8, *(uint4*)&uB[4]);

        // PV both chunks: O^T[d][q] += V^T-frag x P-frag
        __builtin_amdgcn_s_setprio(1);
        o0 = __builtin_amdgcn_mfma_f32_32x32x16_bf16(vfA[0], pA0, o0, 0, 0, 0);
        o0 = __builtin_amdgcn_mfma_f32_32x32x16_bf16(vfA[1], pA1, o0, 0, 0, 0);
        o1 = __builtin_amdgcn_mfma_f32_32x32x16_bf16(vfA[2], pA0, o1, 0, 0, 0);
        o1 = __builtin_amdgcn_mfma_f32_32x32x16_bf16(vfA[3], pA1, o1, 0, 0, 0);
        o0 = __builtin_amdgcn_mfma_f32_32x32x16_bf16(vfB[0], pB0, o0, 0, 0, 0);
        o0 = __builtin_amdgcn_mfma_f32_32x32x16_bf16(vfB[1], pB1, o0, 0, 0, 0);
        o1 = __builtin_amdgcn_mfma_f32_32x32x16_bf16(vfB[2], pB0, o1, 0, 0, 0);
        o1 = __builtin_amdgcn_mfma_f32_32x32x16_bf16(vfB[3], pB1, o1, 0, 0, 0);
        __builtin_amdgcn_s_setprio(0);

        // prefetch next V pair
#pragma unroll
        for (int T = 0; T < 2; T++)
#pragma unroll
            for (int ss = 0; ss < 2; ss++) {
                vfA[T * 2 + ss] = *(const bf16x8*)(vbase + (size_t)(T * 32) * NC + cN + ss * 16);
                vfB[T * 2 + ss] = *(const bf16x8*)(vbase + (size_t)(T * 32) * NC + cN + 32 + ss * 16);
            }
    }

    float l_tot = l_part + __shfl_xor(l_part, 32);
    float inv = 1.0f / l_tot;

    // ---- normalized packed O -> LDS (swizzled)
#pragma unroll
    for (int T = 0; T < 2; T++)
#pragma unroll
        for (int j = 0; j < 8; j++) {
            int dw = T * 16 + (j & 1) + 4 * (j >> 1) + 2 * hi;
            float a = (T == 0) ? o0[2 * j] : o1[2 * j];
            float b = (T == 0) ? o0[2 * j + 1] : o1[2 * j + 1];
            sO[soff(ql, h * 32 + dw)] = pk2(a * inv, b * inv);
        }
    __syncthreads();

    // ---- LayerNorm: wave wid -> rows 4*wid .. 4*wid+3
    float4 g0 = *(const float4*)(ln_g + lane * 8);
    float4 g1 = *(const float4*)(ln_g + lane * 8 + 4);
    float4 b0 = *(const float4*)(ln_b + lane * 8);
    float4 b1 = *(const float4*)(ln_b + lane * 8 + 4);
#pragma unroll
    for (int rr = 0; rr < 4; rr++) {
        int r = wid * 4 + rr;
        uint4 pw = *(const uint4*)(&sO[r * 256 + ((lane ^ (r & 7)) << 2)]);
        float v[8];
        v[0] = bf2f((u16)(pw.x & 0xffff)); v[1] = bf2f((u16)(pw.x >> 16));
        v[2] = bf2f((u16)(pw.y & 0xffff)); v[3] = bf2f((u16)(pw.y >> 16));
        v[4] = bf2f((u16)(pw.z & 0xffff)); v[5] = bf2f((u16)(pw.z >> 16));
        v[6] = bf2f((u16)(pw.w & 0xffff)); v[7] = bf2f((u16)(pw.w >> 16));
        float sum = 0.f, sq = 0.f;
#pragma unroll
        for (int j = 0; j < 8; j++) { sum += v[j]; sq += v[j] * v[j]; }
#pragma unroll
        for (int msk = 1; msk <= 32; msk <<= 1) { sum += __shfl_xor(sum, msk); sq += __shfl_xor(sq, msk); }
        float mu = sum * (1.f / DMODEL);
        float var = sq * (1.f / DMODEL) - mu * mu;
        float rstd = rsqrtf(var + 1e-5f);
        float o[8];
        o[0] = (v[0] - mu) * rstd * g0.x + b0.x; o[1] = (v[1] - mu) * rstd * g0.y + b0.y;
        o[2] = (v[2] - mu) * rstd * g0.z + b0.z; o[3] = (v[3] - mu) * rstd * g0.w + b0.w;
        o[4] = (v[4] - mu) * rstd * g1.x + b1.x; o[5] = (v[5] - mu) * rstd * g1.y + b1.y;
        o[6] = (v[6] - mu) * rstd * g1.z + b1.z; o[7] = (v[7] - mu) * rstd * g1.w + b1.w;
        float* op = Out + (size_t)(q0 + r) * DMODEL + lane * 8;
        *(float4*)op = *(float4*)&o[0];
        *(float4*)(op + 4) = *(float4*)&o[4];
    }
}

extern "C" void kernel_launch(void* const* d_in, const int* in_sizes, int n_in,
                              void* d_out, int out_size, void* d_ws, size_t ws_size,
                              hipStream_t stream)
{
    const float* x      = (const float*)d_in[0];
    const float* W_proj = (const float*)d_in[1];
    const float* b_proj = (const float*)d_in[2];
    const float* W_q    = (const float*)d_in[3];
    const float* b_q    = (const float*)d_in[4];
    const float* W_k    = (const float*)d_in[5];
    const float* b_k    = (const float*)d_in[6];
    const float* W_v    = (const float*)d_in[7];
    const float* b_v    = (const float*)d_in[8];
    const float* k_buf  = (const float*)d_in[9];
    const float* v_buf  = (const float*)d_in[10];
    const float* ln_g   = (const float*)d_in[11];
    const float* ln_b   = (const float*)d_in[12];
    const int*   c_idx  = (const int*)d_in[13];
    float* out = (float*)d_out;

    char* ws = (char*)d_ws;
    size_t off = 0;
    auto alloc = [&](size_t bytes) -> void* {
        void* p = ws + off;
        off += (bytes + 255) & ~(size_t)255;
        return p;
    };
    u16* x_bf   = (u16*)alloc((size_t)NQ * DMODEL * 2);
    u16* kb_bf  = (u16*)alloc((size_t)NC * DMODEL * 2);
    u16* vb_bf  = (u16*)alloc((size_t)NC * DMODEL * 2);
    u16* Wp_bf  = (u16*)alloc((size_t)DMODEL * DMODEL * 2);
    u16* Wq_t   = (u16*)alloc((size_t)DMODEL * DMODEL * 2);
    u16* Wk_t   = (u16*)alloc((size_t)DMODEL * DMODEL * 2);
    u16* Wv_t   = (u16*)alloc((size_t)DMODEL * DMODEL * 2);
    u16* WcombT = (u16*)alloc((size_t)DMODEL * DMODEL * 2);
    u16* Qm     = (u16*)alloc((size_t)NQ * DMODEL * 2);
    u16* Km     = (u16*)alloc((size_t)NC * DMODEL * 2);
    u16* Vtm    = (u16*)alloc((size_t)DMODEL * NC * 2);
    int*   counts = (int*)alloc(NC * 4);
    float* bcomb  = (float*)alloc(DMODEL * 4);
    (void)alloc(262144);   // pad: wrap-free tail prefetch reads past Km/Vtm

    hipMemsetAsync(counts, 0, NC * 4, stream);

    k_prep<<<dim3(7298), dim3(256), 0, stream>>>(
        x, k_buf, v_buf, W_proj, W_q, W_k, W_v, b_proj, b_q, c_idx,
        x_bf, kb_bf, vb_bf, Wp_bf, Wq_t, Wk_t, Wv_t, counts, bcomb);

    // WcombT = Wq^T @ Wp^T  (so Q = x @ (Wp Wq) uses Bt=WcombT)
    k_gemm_bt<0><<<dim3(4, 4), dim3(256), 0, stream>>>(Wq_t, Wp_bf, nullptr, WcombT, DMODEL, DMODEL, DMODEL);
    k_gemm_bt<0><<<dim3(4, 16), dim3(256), 0, stream>>>(kb_bf, Wk_t, b_k, Km, NC, DMODEL, DMODEL);
    k_gemm_bt<1><<<dim3(4, 16), dim3(256), 0, stream>>>(vb_bf, Wv_t, b_v, Vtm, NC, DMODEL, DMODEL);
    k_gemm_bt<0><<<dim3(4, 64), dim3(256), 0, stream>>>(x_bf, WcombT, bcomb, Qm, NQ, DMODEL, DMODEL);

    // scale2 = (1/sqrt(512)) * log2(e); bias in log2 domain (computed in-kernel)
    k_attn5<<<dim3(NQ / 32), dim3(512), 0, stream>>>(Qm, Km, Vtm, counts, ln_g, ln_b, out, 0.06375872f);
    (void)in_sizes; (void)n_in; (void)out_size; (void)ws_size;
}